// Round 4
// baseline (122.215 us; speedup 1.0000x reference)
//
#include <hip/hip_runtime.h>

// EmbedDNF: B=128, IN_F=256, HID=512, OUT=128, E=8 (fp32, e innermost)
//
// impl = 1 - w*(1-xnor) = A + x*Bv ; A = 1 - w*s ; Bv = 2*w*s - w
// H[b,h,e]   = prod_i (A[i,h,e] + x[b,i,e]*Bv[i,h,e])
// out[b,o,e] = 1 - prod_h (1 - dw[h,o,e]*H[b,h,e])
//
// ws: Ht [512][128][8] fp32 (h-major so stage2's streaming read is contiguous)
//
// Access-pattern rules (R3 post-mortem): every global load is either a
// contiguous 512 B wave-segment (lane = ep + 4*hl over the innermost dims)
// or a single 32 B broadcast line (uniform over the 16-lane dim). One i (or h)
// per wave per iteration; the reduction split lives on waves + LDS combine.

static inline __device__ float2 f2mul(float2 a, float2 b) {
    return make_float2(a.x * b.x, a.y * b.y);
}
static inline __device__ float2 f2fma(float2 a, float2 b, float2 c) {
    return make_float2(fmaf(a.x, b.x, c.x), fmaf(a.y, b.y, c.y));
}
static inline __device__ float2 f2nfma1(float2 d, float2 h) {  // 1 - d*h
    return make_float2(fmaf(-d.x, h.x, 1.0f), fmaf(-d.y, h.y, 1.0f));
}

// ---------------------------------------------------------------------------
// Stage 1. Grid 512 = 32 hg (16 h, LOW bits: ~2 MB/XCD L2 slice) x 16 bg (8 b).
// Block 256 = 4 waves = 4 i-chunks of 64. Lane = ep(4 e-pairs) x hl(16 h).
// Thread tile: 8 b x 1 h x 2 e. Per i: 2 contiguous loads (w,s) + 8 broadcast
// x loads; 19 pk-instrs. i-partials combined across waves via LDS.
// ---------------------------------------------------------------------------
__global__ __launch_bounds__(256, 4) void k_stage1(
    const float* __restrict__ in,   // [128][256][8]
    const float* __restrict__ cw,   // [256][512][8]
    const float* __restrict__ cs,   // [256][512][8]
    float* __restrict__ Ht)         // ws: [512][128][8]
{
    __shared__ float2 lds2[4][544];          // [chunk][b*68 + hl*4 + ep], 17.4 KB
    const int t    = threadIdx.x;
    const int lane = t & 63;
    const int w    = t >> 6;                 // i-chunk 0..3
    const int ep   = lane & 3;
    const int hl   = lane >> 2;              // 0..15
    const int hg   = blockIdx.x & 31;
    const int bg   = blockIdx.x >> 5;
    const int h    = hg * 16 + hl;
    const int b0   = bg * 8;
    const int e0   = ep * 2;

    float2 acc[8];
    #pragma unroll
    for (int b = 0; b < 8; ++b) acc[b] = make_float2(1.0f, 1.0f);

    const float* pw = cw + (w * 64) * 4096 + h * 8 + e0;
    const float* ps = cs + (w * 64) * 4096 + h * 8 + e0;
    const float* px = in + b0 * 2048 + (w * 64) * 8 + e0;

    #pragma unroll 4
    for (int i = 0; i < 64; ++i) {
        const float2 wv = *(const float2*)pw;
        const float2 sv = *(const float2*)ps;
        pw += 4096; ps += 4096;
        const float2 p  = f2mul(wv, sv);
        const float2 A  = make_float2(1.0f - p.x, 1.0f - p.y);
        const float2 Bv = make_float2(p.x + p.x - wv.x, p.y + p.y - wv.y);
        #pragma unroll
        for (int b = 0; b < 8; ++b) {
            const float2 xv = *(const float2*)(px + b * 2048);
            acc[b] = f2mul(acc[b], f2fma(xv, Bv, A));
        }
        px += 8;
    }

    #pragma unroll
    for (int b = 0; b < 8; ++b)
        lds2[w][b * 68 + hl * 4 + ep] = acc[b];
    __syncthreads();

    // combine 4 chunks; each thread produces one float4 (2 adjacent float2)
    const int hlo = t >> 4;                  // 0..15
    const int bo  = (t >> 1) & 7;
    const int eq  = t & 1;
    const int i2  = bo * 68 + hlo * 4 + eq * 2;
    float2 m0 = lds2[0][i2];
    float2 m1 = lds2[0][i2 + 1];
    #pragma unroll
    for (int c = 1; c < 4; ++c) {
        m0 = f2mul(m0, lds2[c][i2]);
        m1 = f2mul(m1, lds2[c][i2 + 1]);
    }
    const float4 r = make_float4(m0.x, m0.y, m1.x, m1.y);
    *(float4*)(Ht + (hg * 16 + hlo) * 1024 + (b0 + bo) * 8 + eq * 4) = r;
}

// ---------------------------------------------------------------------------
// Stage 2. Grid 256 = 32 og (4 o, LOW bits: 256 KB/XCD dw slice) x 8 bg (16 b).
// Block 256 = 4 waves = 4 h-chunks of 128. Lane = ep(4) x bl(16 b).
// Thread tile: 4 o x 1 b x 2 e. Per h: 1 contiguous Ht load + 4 broadcast dw
// loads (one 128 B region); 8 pk-instrs. h-partials combined via LDS.
// ---------------------------------------------------------------------------
__global__ __launch_bounds__(256, 4) void k_stage2(
    const float* __restrict__ dw,   // [512][128][8]
    const float* __restrict__ Ht,   // ws: [512][128][8]
    float* __restrict__ out)        // [128][128][8]
{
    __shared__ float2 lds2[4][272];          // [chunk][bl*17 + oj*4 + ep], 8.7 KB
    const int t    = threadIdx.x;
    const int lane = t & 63;
    const int w    = t >> 6;                 // h-chunk 0..3
    const int ep   = lane & 3;
    const int bl   = lane >> 2;              // 0..15
    const int og   = blockIdx.x & 31;
    const int bg   = blockIdx.x >> 5;
    const int b    = bg * 16 + bl;
    const int o0   = og * 4;
    const int e0   = ep * 2;

    float2 acc[4];
    #pragma unroll
    for (int j = 0; j < 4; ++j) acc[j] = make_float2(1.0f, 1.0f);

    const float* ph = Ht + (w * 128) * 1024 + b * 8 + e0;
    const float* pd = dw + (w * 128) * 1024 + o0 * 8 + e0;

    #pragma unroll 4
    for (int i = 0; i < 128; ++i) {
        const float2 hv = *(const float2*)ph;
        float2 dv[4];
        #pragma unroll
        for (int j = 0; j < 4; ++j) dv[j] = *(const float2*)(pd + j * 8);
        ph += 1024; pd += 1024;
        #pragma unroll
        for (int j = 0; j < 4; ++j)
            acc[j] = f2mul(acc[j], f2nfma1(dv[j], hv));
    }

    #pragma unroll
    for (int j = 0; j < 4; ++j)
        lds2[w][bl * 17 + j * 4 + ep] = acc[j];
    __syncthreads();

    // combine 4 chunks; one float2 output per thread
    const int blo = t >> 4;                  // 0..15
    const int rem = t & 15;                  // oj*4 + ep'
    const int i2  = blo * 17 + rem;
    float2 m = lds2[0][i2];
    #pragma unroll
    for (int c = 1; c < 4; ++c) m = f2mul(m, lds2[c][i2]);
    const int oj  = rem >> 2;
    const int epp = rem & 3;
    const float2 r = make_float2(1.0f - m.x, 1.0f - m.y);
    *(float2*)(out + (bg * 16 + blo) * 1024 + (o0 + oj) * 8 + epp * 2) = r;
}

extern "C" void kernel_launch(void* const* d_in, const int* in_sizes, int n_in,
                              void* d_out, int out_size, void* d_ws, size_t ws_size,
                              hipStream_t stream)
{
    const float* in = (const float*)d_in[0];   // [128][256][8]
    const float* cw = (const float*)d_in[1];   // [256][512][8]
    const float* cs = (const float*)d_in[2];   // [256][512][8]
    const float* dw = (const float*)d_in[3];   // [512][128][8]
    float* outp = (float*)d_out;               // [128][128][8]
    float* Ht   = (float*)d_ws;                // 2 MB used

    k_stage1<<<512, 256, 0, stream>>>(in, cw, cs, Ht);
    k_stage2<<<256, 256, 0, stream>>>(dw, Ht, outp);
}